// Round 4
// baseline (693.442 us; speedup 1.0000x reference)
//
#include <hip/hip_runtime.h>
#include <hip/hip_bf16.h>
#include <stdint.h>

typedef unsigned short u16;
typedef __bf16 bf16x8 __attribute__((ext_vector_type(8)));
typedef float floatx16 __attribute__((ext_vector_type(16)));

__device__ __forceinline__ u16 f2bf(float f) {
  union { float f; unsigned u; } c; c.f = f;
  unsigned r = c.u + 0x7fffu + ((c.u >> 16) & 1u);
  return (u16)(r >> 16);
}

__device__ __forceinline__ void load_lds16(const void* g, void* l) {
  __builtin_amdgcn_global_load_lds(
      (const __attribute__((address_space(1))) void*)g,
      (__attribute__((address_space(3))) void*)l,
      16, 0, 0);
}

// ---- preamble: cast x -> bf16 | transpose W0 | transpose W1 | zero z ----
// one launch, block ranges. All blocks 256 threads.
__global__ __launch_bounds__(256) void preamble(
    const float* __restrict__ x, const float* __restrict__ W0,
    const float* __restrict__ W1,
    u16* __restrict__ Xb, u16* __restrict__ Wt0, u16* __restrict__ Wt1,
    float* __restrict__ z)
{
  __shared__ float tile[32][33];
  const int bid = blockIdx.x;
  const int t = threadIdx.x;

  if (bid < 32768) {                      // cast x: 32768*1024 floats, float4/thread
    int i = bid * 256 + t;
    float4 f = ((const float4*)x)[i];
    ushort4 u;
    u.x = f2bf(f.x); u.y = f2bf(f.y); u.z = f2bf(f.z); u.w = f2bf(f.w);
    ((ushort4*)Xb)[i] = u;
  } else if (bid < 32768 + 2048) {        // transpose W0 [1024,2048] -> [2048,1024]
    int tb = bid - 32768;
    int bx = (tb & 63) * 32, by = (tb >> 6) * 32;
    int tx = t & 31, ty = t >> 5;
    #pragma unroll
    for (int i = 0; i < 32; i += 8)
      tile[ty + i][tx] = W0[(size_t)(by + ty + i) * 2048 + bx + tx];
    __syncthreads();
    #pragma unroll
    for (int i = 0; i < 32; i += 8)
      Wt0[(size_t)(bx + ty + i) * 1024 + by + tx] = f2bf(tile[tx][ty + i]);
  } else if (bid < 32768 + 2048 + 4096) { // transpose W1 [2048,2048]
    int tb = bid - (32768 + 2048);
    int bx = (tb & 63) * 32, by = (tb >> 6) * 32;
    int tx = t & 31, ty = t >> 5;
    #pragma unroll
    for (int i = 0; i < 32; i += 8)
      tile[ty + i][tx] = W1[(size_t)(by + ty + i) * 2048 + bx + tx];
    __syncthreads();
    #pragma unroll
    for (int i = 0; i < 32; i += 8)
      Wt1[(size_t)(bx + ty + i) * 2048 + by + tx] = f2bf(tile[tx][ty + i]);
  } else {                                // zero z[32768]: 32 blocks x 256 x float4
    int tb = bid - (32768 + 2048 + 4096);
    ((float4*)z)[tb * 256 + t] = (float4){0.f, 0.f, 0.f, 0.f};
  }
}

// ------------- GEMM: elu(A[M,K] @ Bt[N,K]^T + bias), bf16 in -------------
// 128x128 block tile, BK=64, 4 waves at 64x64, 32x32x16 bf16 MFMA (2382 TF
// pipe vs 2075 for 16x16x32; half the MFMA instruction count), width-16
// global_load_lds staging, XOR chunk swizzle (R3: verified 0 bank conflicts).
//
// LDS tile [128][64] u16: stored 16B chunk sc of row r holds logical chunk
// sc^(r&7); staging permutes the global source within each 128B row segment.
//
// 32x32x16 fragment layouts:
//   A: lane l holds m = l&31, k = (l>>5)*8 + j  (j=0..7) -> one b128 read
//   C/D: col = l&31, row = (reg&3) + 8*(reg>>2) + 4*(l>>5)   [m74/m101]
template<bool FUSE_HEAD>
__global__ __launch_bounds__(256) void gemm_bt_fused(
    const u16* __restrict__ A,      // [M, K] bf16
    const u16* __restrict__ Bt,     // [N, K] bf16
    const float* __restrict__ bias, // [N]
    u16* __restrict__ C,            // [M, N] bf16 (unused if FUSE_HEAD)
    const float* __restrict__ W2,   // [N] (used if FUSE_HEAD)
    float* __restrict__ z,          // [M] fp32 accum (used if FUSE_HEAD)
    int M, int N, int K)
{
  __shared__ u16 As[128 * 64];
  __shared__ u16 Bs[128 * 64];

  const int t = threadIdx.x;
  const int w = t >> 6;        // wave 0..3
  const int l = t & 63;
  const int wm = w >> 1;       // wave row (0/1)
  const int wn = w & 1;        // wave col (0/1)
  const int lm = l & 31;       // row/col within 32-tile
  const int h  = l >> 5;       // half (0/1)

  const int n0 = blockIdx.x * 128;
  const int m0 = blockIdx.y * 128;

  floatx16 acc[2][2];
  #pragma unroll
  for (int i = 0; i < 2; ++i)
    #pragma unroll
    for (int j = 0; j < 2; ++j)
      acc[i][j] = (floatx16)(0.f);

  // ---- staging geometry: instr k (0..3) per matrix; LDS dest (k*256+t)*8,
  // row = k*32 + (t>>3), stored chunk t&7, logical chunk (t&7)^(row&7) ----
  const int rowoff = t >> 3;
  const int lc8 = ((t & 7) ^ (rowoff & 7)) * 8;
  const u16* Ap[4];
  const u16* Bp[4];
  #pragma unroll
  for (int k = 0; k < 4; ++k) {
    Ap[k] = A  + (size_t)(m0 + k * 32 + rowoff) * K + lc8;
    Bp[k] = Bt + (size_t)(n0 + k * 32 + rowoff) * K + lc8;
  }
  const int ldsoff = t * 8;

  // read rows: A row = wm*64 + i*32 + lm (row&7 == lm&7), logical chunk s*2+h
  const int arow0 = (wm * 64 + lm) * 64;        // + i*32*64
  const int brow0 = (wn * 64 + lm) * 64;
  const int swb = (lm & 7);

  for (int k0 = 0; k0 < K; k0 += 64) {
    __syncthreads();
    #pragma unroll
    for (int k = 0; k < 4; ++k) {
      load_lds16(Ap[k] + k0, &As[k * 2048 + ldsoff]);
      load_lds16(Bp[k] + k0, &Bs[k * 2048 + ldsoff]);
    }
    __syncthreads();

    #pragma unroll
    for (int s = 0; s < 4; ++s) {
      const int sw = ((s * 2 + h) ^ swb) * 8;
      bf16x8 af[2], bfr[2];
      #pragma unroll
      for (int i = 0; i < 2; ++i)
        af[i] = *(const bf16x8*)(As + arow0 + i * 32 * 64 + sw);
      #pragma unroll
      for (int j = 0; j < 2; ++j)
        bfr[j] = *(const bf16x8*)(Bs + brow0 + j * 32 * 64 + sw);
      #pragma unroll
      for (int i = 0; i < 2; ++i)
        #pragma unroll
        for (int j = 0; j < 2; ++j)
          acc[i][j] = __builtin_amdgcn_mfma_f32_32x32x16_bf16(af[i], bfr[j], acc[i][j], 0, 0, 0);
    }
  }

  float bv[2];
  #pragma unroll
  for (int j = 0; j < 2; ++j) bv[j] = bias[n0 + wn * 64 + j * 32 + lm];

  if (!FUSE_HEAD) {
    #pragma unroll
    for (int i = 0; i < 2; ++i) {
      #pragma unroll
      for (int r = 0; r < 16; ++r) {
        int row = m0 + wm * 64 + i * 32 + (r & 3) + 8 * (r >> 2) + 4 * h;
        size_t base = (size_t)row * N + n0 + wn * 64 + lm;
        #pragma unroll
        for (int j = 0; j < 2; ++j) {
          float v = acc[i][j][r] + bv[j];
          v = v > 0.f ? v : (__expf(v) - 1.f);
          C[base + j * 32] = f2bf(v);
        }
      }
    }
  } else {
    float w2v[2];
    #pragma unroll
    for (int j = 0; j < 2; ++j) w2v[j] = W2[n0 + wn * 64 + j * 32 + lm];
    #pragma unroll
    for (int i = 0; i < 2; ++i) {
      #pragma unroll
      for (int r = 0; r < 16; ++r) {
        float p = 0.f;
        #pragma unroll
        for (int j = 0; j < 2; ++j) {
          float v = acc[i][j][r] + bv[j];
          v = v > 0.f ? v : (__expf(v) - 1.f);
          p += v * w2v[j];
        }
        p += __shfl_xor(p, 1);
        p += __shfl_xor(p, 2);
        p += __shfl_xor(p, 4);
        p += __shfl_xor(p, 8);
        p += __shfl_xor(p, 16);
        if (lm == 0)
          atomicAdd(&z[m0 + wm * 64 + i * 32 + (r & 3) + 8 * (r >> 2) + 4 * h], p);
      }
    }
  }
}

// ------------- finish: out = sigmoid(z + b2); alpha = acti(out) -------------
__global__ __launch_bounds__(256) void sigmoid_alpha(
    const float* __restrict__ z, const float* __restrict__ b2,
    float* __restrict__ out, int B)
{
  int i = blockIdx.x * blockDim.x + threadIdx.x;
  if (i >= B) return;
  float o = 1.f / (1.f + expf(-(z[i] + b2[0])));
  float alpha;
  if (o <= 0.2f)      alpha = 0.1f - 0.5f * o;
  else if (o >= 0.8f) alpha = 0.5f * o - 0.4f;
  else                alpha = 0.f;
  out[i] = o;
  out[B + i] = alpha;
}

extern "C" void kernel_launch(void* const* d_in, const int* in_sizes, int n_in,
                              void* d_out, int out_size, void* d_ws, size_t ws_size,
                              hipStream_t stream) {
  const int BATCH = 32768, IN = 1024, HID = 2048;

  const float* x  = (const float*)d_in[0];
  const float* W0 = (const float*)d_in[1];
  const float* b0 = (const float*)d_in[2];
  const float* W1 = (const float*)d_in[3];
  const float* b1 = (const float*)d_in[4];
  const float* W2 = (const float*)d_in[5];
  const float* b2 = (const float*)d_in[6];
  float* out = (float*)d_out;

  char* ws = (char*)d_ws;
  u16* Xb   = (u16*)(ws);                       // 64 MB [32768,1024]
  u16* Wt0  = (u16*)(ws + (size_t)67108864);    // 4 MB  [2048,1024]
  u16* Wt1  = (u16*)(ws + (size_t)71303168);    // 8 MB  [2048,2048]
  u16* h0   = (u16*)(ws + (size_t)79691776);    // 128 MB [32768,2048]
  float* z  = (float*)(ws + (size_t)213909504); // 128 KB [32768]

  // 1) preamble: cast x, transpose W0/W1, zero z  (32768+2048+4096+32 blocks)
  preamble<<<32768 + 2048 + 4096 + 32, 256, 0, stream>>>(x, W0, W1, Xb, Wt0, Wt1, z);
  // 2) h0 = elu(Xb @ Wt0^T + b0)
  gemm_bt_fused<false><<<dim3(HID / 128, BATCH / 128), 256, 0, stream>>>(
      Xb, Wt0, b0, h0, nullptr, nullptr, BATCH, HID, IN);
  // 3) z += rows of elu(h0 @ Wt1^T + b1) dotted with W2 (h1 never stored)
  gemm_bt_fused<true><<<dim3(HID / 128, BATCH / 128), 256, 0, stream>>>(
      h0, Wt1, b1, nullptr, W2, z, BATCH, HID, HID);
  // 4) out + alpha
  sigmoid_alpha<<<BATCH / 256, 256, 0, stream>>>(z, b2, out, BATCH);
}

// Round 5
// 662.601 us; speedup vs baseline: 1.0465x; 1.0465x over previous
//
#include <hip/hip_runtime.h>
#include <hip/hip_bf16.h>
#include <stdint.h>

typedef unsigned short u16;
typedef __bf16 bf16x8 __attribute__((ext_vector_type(8)));
typedef float floatx4 __attribute__((ext_vector_type(4)));

__device__ __forceinline__ u16 f2bf(float f) {
  union { float f; unsigned u; } c; c.f = f;
  unsigned r = c.u + 0x7fffu + ((c.u >> 16) & 1u);
  return (u16)(r >> 16);
}

__device__ __forceinline__ void load_lds16(const void* g, void* l) {
  __builtin_amdgcn_global_load_lds(
      (const __attribute__((address_space(1))) void*)g,
      (__attribute__((address_space(3))) void*)l,
      16, 0, 0);
}

// ---- preamble: cast x -> bf16 | transpose W0 | transpose W1 | zero z ----
// one launch, block ranges; saved ~40us vs separate dispatches (R4 data).
__global__ __launch_bounds__(256) void preamble(
    const float* __restrict__ x, const float* __restrict__ W0,
    const float* __restrict__ W1,
    u16* __restrict__ Xb, u16* __restrict__ Wt0, u16* __restrict__ Wt1,
    float* __restrict__ z)
{
  __shared__ float tile[32][33];
  const int bid = blockIdx.x;
  const int t = threadIdx.x;

  if (bid < 32768) {                      // cast x: 32768*1024 floats, float4/thread
    int i = bid * 256 + t;
    float4 f = ((const float4*)x)[i];
    ushort4 u;
    u.x = f2bf(f.x); u.y = f2bf(f.y); u.z = f2bf(f.z); u.w = f2bf(f.w);
    ((ushort4*)Xb)[i] = u;
  } else if (bid < 32768 + 2048) {        // transpose W0 [1024,2048] -> [2048,1024]
    int tb = bid - 32768;
    int bx = (tb & 63) * 32, by = (tb >> 6) * 32;
    int tx = t & 31, ty = t >> 5;
    #pragma unroll
    for (int i = 0; i < 32; i += 8)
      tile[ty + i][tx] = W0[(size_t)(by + ty + i) * 2048 + bx + tx];
    __syncthreads();
    #pragma unroll
    for (int i = 0; i < 32; i += 8)
      Wt0[(size_t)(bx + ty + i) * 1024 + by + tx] = f2bf(tile[tx][ty + i]);
  } else if (bid < 32768 + 2048 + 4096) { // transpose W1 [2048,2048]
    int tb = bid - (32768 + 2048);
    int bx = (tb & 63) * 32, by = (tb >> 6) * 32;
    int tx = t & 31, ty = t >> 5;
    #pragma unroll
    for (int i = 0; i < 32; i += 8)
      tile[ty + i][tx] = W1[(size_t)(by + ty + i) * 2048 + bx + tx];
    __syncthreads();
    #pragma unroll
    for (int i = 0; i < 32; i += 8)
      Wt1[(size_t)(bx + ty + i) * 2048 + by + tx] = f2bf(tile[tx][ty + i]);
  } else {                                // zero z[32768]: 32 blocks x 256 x float4
    int tb = bid - (32768 + 2048 + 4096);
    ((float4*)z)[tb * 256 + t] = (float4){0.f, 0.f, 0.f, 0.f};
  }
}

// ------------- GEMM: elu(A[M,K] @ Bt[N,K]^T + bias), bf16 in -------------
// R3-verified configuration: 128x128 block tile, BK=64, 4 waves at 64x64,
// 16x16x32 bf16 MFMA, width-16 global_load_lds staging, XOR chunk swizzle.
// Measured R3: 873 TF on GEMM2, SQ_LDS_BANK_CONFLICT == 0.
// NOTE: do NOT switch to 32x32x16 — R4 measured +4 cyc/ds_read_b128 bank
// conflict with that shape's read pattern (lm=l&31) and a 315->365us
// regression, despite identical staging.
//
// LDS tile [128][64] u16: stored 16B chunk sc of row r holds logical chunk
// sc^(r&7); staging permutes the GLOBAL source within each 128B row segment
// (coalescing preserved; LDS dest stays the HW-forced base+lane*16B).
//
// FUSE_HEAD: instead of storing C, compute per-row partial dot with W2
// (fp32), butterfly-reduce over the 16-lane col group, atomicAdd into z[M].
template<bool FUSE_HEAD>
__global__ __launch_bounds__(256) void gemm_bt_fused(
    const u16* __restrict__ A,      // [M, K] bf16
    const u16* __restrict__ Bt,     // [N, K] bf16
    const float* __restrict__ bias, // [N]
    u16* __restrict__ C,            // [M, N] bf16 (unused if FUSE_HEAD)
    const float* __restrict__ W2,   // [N] (used if FUSE_HEAD)
    float* __restrict__ z,          // [M] fp32 accum (used if FUSE_HEAD)
    int M, int N, int K)
{
  __shared__ u16 As[128 * 64];
  __shared__ u16 Bs[128 * 64];

  const int t = threadIdx.x;
  const int w = t >> 6;        // wave 0..3
  const int l = t & 63;        // lane
  const int wm = w >> 1;       // wave row (0/1)
  const int wn = w & 1;        // wave col (0/1)
  const int lm = l & 15;
  const int q  = l >> 4;       // quad 0..3

  const int n0 = blockIdx.x * 128;
  const int m0 = blockIdx.y * 128;

  floatx4 acc[4][4];
  #pragma unroll
  for (int i = 0; i < 4; ++i)
    #pragma unroll
    for (int j = 0; j < 4; ++j)
      acc[i][j] = (floatx4){0.f, 0.f, 0.f, 0.f};

  // ---- staging geometry: instr k (0..3) per matrix; LDS dest (k*256+t)*8,
  // row = k*32 + (t>>3), stored chunk t&7, logical chunk (t&7)^(row&7) ----
  const int rowoff = t >> 3;                    // 0..31
  const int lc8 = ((t & 7) ^ (rowoff & 7)) * 8; // u16 offset in row
  const u16* Ap[4];
  const u16* Bp[4];
  #pragma unroll
  for (int k = 0; k < 4; ++k) {
    Ap[k] = A  + (size_t)(m0 + k * 32 + rowoff) * K + lc8;
    Bp[k] = Bt + (size_t)(n0 + k * 32 + rowoff) * K + lc8;
  }
  const int ldsoff = t * 8;  // + k*2048

  // ---- read-side swizzled chunk offsets: logical chunk s*4+q of row lm ----
  const int sw0 = ((0 * 4 + q) ^ (lm & 7)) * 8;
  const int sw1 = ((1 * 4 + q) ^ (lm & 7)) * 8;

  for (int k0 = 0; k0 < K; k0 += 64) {
    __syncthreads();
    #pragma unroll
    for (int k = 0; k < 4; ++k) {
      load_lds16(Ap[k] + k0, &As[k * 2048 + ldsoff]);
      load_lds16(Bp[k] + k0, &Bs[k * 2048 + ldsoff]);
    }
    __syncthreads();

    // s = 0 half (k 0..31)
    {
      bf16x8 af[4], bfr[4];
      #pragma unroll
      for (int i = 0; i < 4; ++i)
        af[i] = *(const bf16x8*)(As + (wm * 64 + i * 16 + lm) * 64 + sw0);
      #pragma unroll
      for (int j = 0; j < 4; ++j)
        bfr[j] = *(const bf16x8*)(Bs + (wn * 64 + j * 16 + lm) * 64 + sw0);
      #pragma unroll
      for (int i = 0; i < 4; ++i)
        #pragma unroll
        for (int j = 0; j < 4; ++j)
          acc[i][j] = __builtin_amdgcn_mfma_f32_16x16x32_bf16(af[i], bfr[j], acc[i][j], 0, 0, 0);
    }
    // s = 1 half (k 32..63)
    {
      bf16x8 af[4], bfr[4];
      #pragma unroll
      for (int i = 0; i < 4; ++i)
        af[i] = *(const bf16x8*)(As + (wm * 64 + i * 16 + lm) * 64 + sw1);
      #pragma unroll
      for (int j = 0; j < 4; ++j)
        bfr[j] = *(const bf16x8*)(Bs + (wn * 64 + j * 16 + lm) * 64 + sw1);
      #pragma unroll
      for (int i = 0; i < 4; ++i)
        #pragma unroll
        for (int j = 0; j < 4; ++j)
          acc[i][j] = __builtin_amdgcn_mfma_f32_16x16x32_bf16(af[i], bfr[j], acc[i][j], 0, 0, 0);
    }
  }

  float bv[4];
  #pragma unroll
  for (int j = 0; j < 4; ++j) bv[j] = bias[n0 + wn * 64 + j * 16 + lm];

  if (!FUSE_HEAD) {
    // bias + ELU, store bf16
    #pragma unroll
    for (int i = 0; i < 4; ++i) {
      #pragma unroll
      for (int r = 0; r < 4; ++r) {
        int grow = m0 + wm * 64 + i * 16 + q * 4 + r;
        size_t base = (size_t)grow * N + n0 + wn * 64 + lm;
        #pragma unroll
        for (int j = 0; j < 4; ++j) {
          float v = acc[i][j][r] + bv[j];
          v = v > 0.f ? v : (__expf(v) - 1.f);
          C[base + j * 16] = f2bf(v);
        }
      }
    }
  } else {
    // bias + ELU + partial dot with W2; reduce over the 16-lane col group
    float w2v[4];
    #pragma unroll
    for (int j = 0; j < 4; ++j) w2v[j] = W2[n0 + wn * 64 + j * 16 + lm];
    #pragma unroll
    for (int i = 0; i < 4; ++i) {
      #pragma unroll
      for (int r = 0; r < 4; ++r) {
        float p = 0.f;
        #pragma unroll
        for (int j = 0; j < 4; ++j) {
          float v = acc[i][j][r] + bv[j];
          v = v > 0.f ? v : (__expf(v) - 1.f);
          p += v * w2v[j];
        }
        p += __shfl_xor(p, 1);
        p += __shfl_xor(p, 2);
        p += __shfl_xor(p, 4);
        p += __shfl_xor(p, 8);
        if (lm == 0) atomicAdd(&z[m0 + wm * 64 + i * 16 + q * 4 + r], p);
      }
    }
  }
}

// ------------- finish: out = sigmoid(z + b2); alpha = acti(out) -------------
__global__ __launch_bounds__(256) void sigmoid_alpha(
    const float* __restrict__ z, const float* __restrict__ b2,
    float* __restrict__ out, int B)
{
  int i = blockIdx.x * blockDim.x + threadIdx.x;
  if (i >= B) return;
  float o = 1.f / (1.f + expf(-(z[i] + b2[0])));
  float alpha;
  if (o <= 0.2f)      alpha = 0.1f - 0.5f * o;
  else if (o >= 0.8f) alpha = 0.5f * o - 0.4f;
  else                alpha = 0.f;
  out[i] = o;
  out[B + i] = alpha;
}

extern "C" void kernel_launch(void* const* d_in, const int* in_sizes, int n_in,
                              void* d_out, int out_size, void* d_ws, size_t ws_size,
                              hipStream_t stream) {
  const int BATCH = 32768, IN = 1024, HID = 2048;

  const float* x  = (const float*)d_in[0];
  const float* W0 = (const float*)d_in[1];
  const float* b0 = (const float*)d_in[2];
  const float* W1 = (const float*)d_in[3];
  const float* b1 = (const float*)d_in[4];
  const float* W2 = (const float*)d_in[5];
  const float* b2 = (const float*)d_in[6];
  float* out = (float*)d_out;

  char* ws = (char*)d_ws;
  u16* Xb   = (u16*)(ws);                       // 64 MB [32768,1024]
  u16* Wt0  = (u16*)(ws + (size_t)67108864);    // 4 MB  [2048,1024]
  u16* Wt1  = (u16*)(ws + (size_t)71303168);    // 8 MB  [2048,2048]
  u16* h0   = (u16*)(ws + (size_t)79691776);    // 128 MB [32768,2048]
  float* z  = (float*)(ws + (size_t)213909504); // 128 KB [32768]

  // 1) preamble: cast x, transpose W0/W1, zero z
  preamble<<<32768 + 2048 + 4096 + 32, 256, 0, stream>>>(x, W0, W1, Xb, Wt0, Wt1, z);
  // 2) h0 = elu(Xb @ Wt0^T + b0)
  gemm_bt_fused<false><<<dim3(HID / 128, BATCH / 128), 256, 0, stream>>>(
      Xb, Wt0, b0, h0, nullptr, nullptr, BATCH, HID, IN);
  // 3) z += rows of elu(h0 @ Wt1^T + b1) dotted with W2 (h1 never stored)
  gemm_bt_fused<true><<<dim3(HID / 128, BATCH / 128), 256, 0, stream>>>(
      h0, Wt1, b1, nullptr, W2, z, BATCH, HID, HID);
  // 4) out + alpha
  sigmoid_alpha<<<BATCH / 256, 256, 0, stream>>>(z, b2, out, BATCH);
}